// Round 10
// baseline (747.620 us; speedup 1.0000x reference)
//
#include <hip/hip_runtime.h>
#include <math.h>

// Problem constants
#define B_  4
#define L_  2048
#define D_  1024
#define H_  16
#define HD_ 64

typedef __attribute__((ext_vector_type(8))) short short8;
typedef __attribute__((ext_vector_type(4))) float f32x4;
typedef __attribute__((ext_vector_type(16))) float f32x16;
typedef __attribute__((ext_vector_type(4))) int   i32x4;

// fp32 -> bf16 bits, round-to-nearest-even
__device__ static inline unsigned short f2bf(float f) {
    union { float f; unsigned int u; } v; v.f = f;
    const unsigned int u = v.u;
    return (unsigned short)((u + 0x7FFFu + ((u >> 16) & 1u)) >> 16);
}

// packed fp32x2 -> bf16x2 (single VALU op; T12 primitive)
__device__ static inline unsigned cvt_pk_bf16(float a, float b) {
    unsigned r;
    asm("v_cvt_pk_bf16_f32 %0, %1, %2" : "=v"(r) : "v"(a), "v"(b));
    return r;
}

__device__ static inline void async_copy16(const void* g, void* lds)
{
    __builtin_amdgcn_global_load_lds(
        (const __attribute__((address_space(1))) void*)g,
        (__attribute__((address_space(3))) void*)lds, 16, 0, 0);
}

// ---------------------------------------------------------------------------
// fp32 -> bf16 convert, 8 elem/thread, 3 tensors in one launch (y selects)
// ---------------------------------------------------------------------------
__global__ __launch_bounds__(256) void cvt3_bf16_kernel(
    const float* __restrict__ i0, const float* __restrict__ i1,
    const float* __restrict__ i2,
    unsigned short* __restrict__ o0, unsigned short* __restrict__ o1,
    unsigned short* __restrict__ o2)
{
    const float* in = blockIdx.y == 0 ? i0 : blockIdx.y == 1 ? i1 : i2;
    unsigned short* out = blockIdx.y == 0 ? o0 : blockIdx.y == 1 ? o1 : o2;
    const size_t i = ((size_t)blockIdx.x * 256 + threadIdx.x) * 8;
    const float4 x = *(const float4*)&in[i];
    const float4 y = *(const float4*)&in[i + 4];
    ushort4 a0, a1;
    a0.x = f2bf(x.x); a0.y = f2bf(x.y); a0.z = f2bf(x.z); a0.w = f2bf(x.w);
    a1.x = f2bf(y.x); a1.y = f2bf(y.y); a1.z = f2bf(y.z); a1.w = f2bf(y.w);
    *(ushort4*)&out[i]     = a0;
    *(ushort4*)&out[i + 4] = a1;
}

// ---------------------------------------------------------------------------
// Transpose + convert: WT[n][k] = bf16(W[k][n]), square N=1024
// ---------------------------------------------------------------------------
__global__ __launch_bounds__(256) void transpose_bf16_kernel(
    const float* __restrict__ W, unsigned short* __restrict__ WT)
{
    __shared__ float t[32][33];
    const int c  = threadIdx.x & 31;
    const int r8 = threadIdx.x >> 5;          // 0..7
    const int k0 = blockIdx.y * 32;
    const int n0 = blockIdx.x * 32;
    #pragma unroll
    for (int i = 0; i < 4; ++i) {
        const int r = r8 + i * 8;
        t[r][c] = W[(size_t)(k0 + r) * 1024 + n0 + c];
    }
    __syncthreads();
    #pragma unroll
    for (int i = 0; i < 4; ++i) {
        const int r = r8 + i * 8;
        WT[(size_t)(n0 + r) * 1024 + k0 + c] = f2bf(t[c][r]);
    }
}

// 3 weight transposes in one launch (z selects)
__global__ __launch_bounds__(256) void trans3_bf16_kernel(
    const float* __restrict__ W0, const float* __restrict__ W1,
    const float* __restrict__ W2,
    unsigned short* __restrict__ T0, unsigned short* __restrict__ T1,
    unsigned short* __restrict__ T2)
{
    __shared__ float t[32][33];
    const float* W = blockIdx.z == 0 ? W0 : blockIdx.z == 1 ? W1 : W2;
    unsigned short* WT = blockIdx.z == 0 ? T0 : blockIdx.z == 1 ? T1 : T2;
    const int c  = threadIdx.x & 31;
    const int r8 = threadIdx.x >> 5;
    const int k0 = blockIdx.y * 32;
    const int n0 = blockIdx.x * 32;
    #pragma unroll
    for (int i = 0; i < 4; ++i) {
        const int r = r8 + i * 8;
        t[r][c] = W[(size_t)(k0 + r) * 1024 + n0 + c];
    }
    __syncthreads();
    #pragma unroll
    for (int i = 0; i < 4; ++i) {
        const int r = r8 + i * 8;
        WT[(size_t)(n0 + r) * 1024 + k0 + c] = f2bf(t[c][r]);
    }
}

// ---------------------------------------------------------------------------
// Pack mask -> key-tile-major 64-bit row words (as 2x uint32):
// mm[((b*32 + kt)*2048 + q)*2 + w] bit j = mask key kt*64 + w*32 + j
// ---------------------------------------------------------------------------
__global__ __launch_bounds__(256) void pack_mask32_kernel(
    const int* __restrict__ mask, unsigned int* __restrict__ mm)
{
    const unsigned g = blockIdx.x * 256 + threadIdx.x;
    const int v = mask[g];
    const unsigned long long bm = __ballot(v != 0);
    const int lane = threadIdx.x & 63;
    const int b = g >> 22;
    const int q = (g >> 11) & 2047;
    const int k = g & 2047;
    const unsigned idx = ((unsigned)(b * 32 + (k >> 6)) * 2048 + q) * 2 + ((k >> 5) & 1);
    if (lane == 0)       mm[idx] = (unsigned)bm;
    else if (lane == 32) mm[idx] = (unsigned)(bm >> 32);
}

// ---------------------------------------------------------------------------
// bf16 MFMA GEMM body (m97 recipe). vmode=1: write bf16 TRANSPOSED into
// vtb[b][h][d][l] (fuses the V transpose into the V-projection epilogue).
// ---------------------------------------------------------------------------
template<int OUT_BF16>
__device__ static inline void gemm_body(
    const unsigned short* __restrict__ A, const unsigned short* __restrict__ WT,
    const float* __restrict__ bias, void* __restrict__ Cv,
    int M, int N, int K, float omul, int vmode,
    unsigned short* At, unsigned short* Bt)
{
    const int tid  = threadIdx.x;
    const int lane = tid & 63;
    const int wave = tid >> 6;
    const int wm   = wave >> 1;
    const int wn   = wave & 1;
    const int quad = lane >> 4;
    const int l15  = lane & 15;
    const int m0   = blockIdx.y * 128;
    const int n0   = blockIdx.x * 128;

    f32x4 acc[4][4];
    #pragma unroll
    for (int i = 0; i < 4; ++i)
        #pragma unroll
        for (int j = 0; j < 4; ++j) acc[i][j] = (f32x4)0.f;

    for (int k0 = 0; k0 < K; k0 += 64) {
        __syncthreads();
        #pragma unroll
        for (int i = 0; i < 4; ++i) {
            const int fb  = i * 256 + wave * 64;
            const int f   = fb + lane;
            const int row = f >> 3;
            const int c8  = f & 7;
            async_copy16(&A [(size_t)(m0 + row) * K + k0 + c8 * 8],
                         (char*)At + (size_t)fb * 16);
            async_copy16(&WT[(size_t)(n0 + row) * K + k0 + c8 * 8],
                         (char*)Bt + (size_t)fb * 16);
        }
        __syncthreads();

        #pragma unroll
        for (int kk = 0; kk < 64; kk += 32) {
            short8 afr[4], bfr[4];
            #pragma unroll
            for (int mt = 0; mt < 4; ++mt)
                afr[mt] = *(const short8*)&At[(size_t)(wm * 64 + mt * 16 + l15) * 64 + kk + quad * 8];
            #pragma unroll
            for (int nt = 0; nt < 4; ++nt)
                bfr[nt] = *(const short8*)&Bt[(size_t)(wn * 64 + nt * 16 + l15) * 64 + kk + quad * 8];
            __builtin_amdgcn_s_setprio(1);
            #pragma unroll
            for (int mt = 0; mt < 4; ++mt)
                #pragma unroll
                for (int nt = 0; nt < 4; ++nt)
                    acc[mt][nt] = __builtin_amdgcn_mfma_f32_16x16x32_bf16(
                        afr[mt], bfr[nt], acc[mt][nt], 0, 0, 0);
            __builtin_amdgcn_s_setprio(0);
        }
    }

    if (OUT_BF16 && vmode) {
        // transposed V epilogue: Cv = vtb[b][h][d][l]
        #pragma unroll
        for (int nt = 0; nt < 4; ++nt) {
            const int col = n0 + wn * 64 + nt * 16 + l15;
            const float bv = bias[col];
            const int hh = col >> 6, dl = col & 63;
            #pragma unroll
            for (int mt = 0; mt < 4; ++mt) {
                const int m  = m0 + wm * 64 + mt * 16 + quad * 4;
                const int bb = m >> 11, ll = m & 2047;
                ushort4 o;
                o.x = f2bf(acc[mt][nt][0] + bv);
                o.y = f2bf(acc[mt][nt][1] + bv);
                o.z = f2bf(acc[mt][nt][2] + bv);
                o.w = f2bf(acc[mt][nt][3] + bv);
                *(ushort4*)&((unsigned short*)Cv)[
                    ((size_t)(bb * H_ + hh) * 64 + dl) * 2048 + ll] = o;
            }
        }
        return;
    }

    #pragma unroll
    for (int nt = 0; nt < 4; ++nt) {
        const int col = n0 + wn * 64 + nt * 16 + l15;
        const float bv = bias[col];
        #pragma unroll
        for (int mt = 0; mt < 4; ++mt) {
            const int r0 = m0 + wm * 64 + mt * 16 + quad * 4;
            #pragma unroll
            for (int r = 0; r < 4; ++r) {
                const float val = (acc[mt][nt][r] + bv) * omul;
                if constexpr (OUT_BF16)
                    ((unsigned short*)Cv)[(size_t)(r0 + r) * N + col] = f2bf(val);
                else
                    ((float*)Cv)[(size_t)(r0 + r) * N + col] = val;
            }
        }
    }
}

// Q/K/V projections in ONE launch (z selects); bf16 out; V written transposed.
__global__ __launch_bounds__(256) void gemm3_mfma_kernel(
    const unsigned short* __restrict__ A0, const unsigned short* __restrict__ A1,
    const unsigned short* __restrict__ A2,
    const unsigned short* __restrict__ W0, const unsigned short* __restrict__ W1,
    const unsigned short* __restrict__ W2,
    const float* __restrict__ b0, const float* __restrict__ b1,
    const float* __restrict__ b2,
    unsigned short* __restrict__ C0, unsigned short* __restrict__ C1,
    unsigned short* __restrict__ C2, float om0)
{
    __shared__ __align__(16) unsigned short At[128 * 64];
    __shared__ __align__(16) unsigned short Bt[128 * 64];
    const int z = blockIdx.z;
    const unsigned short* A  = z == 0 ? A0 : z == 1 ? A1 : A2;
    const unsigned short* WT = z == 0 ? W0 : z == 1 ? W1 : W2;
    const float* bias        = z == 0 ? b0 : z == 1 ? b1 : b2;
    unsigned short* C        = z == 0 ? C0 : z == 1 ? C1 : C2;
    const float omul         = z == 0 ? om0 : 1.f;
    gemm_body<1>(A, WT, bias, C, B_ * L_, D_, D_, omul, z == 2, At, Bt);
}

// Single GEMM, fp32 out (final projection)
__global__ __launch_bounds__(256) void gemm_mfma_kernel(
    const unsigned short* __restrict__ A, const unsigned short* __restrict__ WT,
    const float* __restrict__ bias, float* __restrict__ C,
    int M, int N, int K)
{
    __shared__ __align__(16) unsigned short At[128 * 64];
    __shared__ __align__(16) unsigned short Bt[128 * 64];
    gemm_body<0>(A, WT, bias, C, M, N, K, 1.f, 0, At, Bt);
}

// ---------------------------------------------------------------------------
// MFMA flash attention, 32x32x16 core, software-pipelined (T15 analog).
// Verified R8 structure + QK(t+1) computed ADJACENT to SM(t) so the wave's
// own MFMA stream interleaves with its VALU stream (separate pipes).
// Buffering (one barrier/tile, race-free by consumption order):
//   iter t: issue K(t+2)->Kb[t%2] (K(t) died in iter t-1's QK),
//           issue V(t+1)->Vb[(t+1)%2] (V(t-1) died in iter t-1's PV),
//           QK(t+1) from Kb[(t+1)%2]  ||  SM(t) on stPrev,
//           PV(t) from Vb[t%2], barrier.
// Mask: per-lane 8B global load (row q broadcast across halves) - no LDS.
// LDS = 32KB -> 4 blocks/CU. Regs: stPrev+stNext+ot+qf = 112 < 128 cap.
// ---------------------------------------------------------------------------
#define AQ 128
#define AK 64
#define NT (L_ / AK)

__global__ __launch_bounds__(256, 4) void attn_mfma_kernel(
    const unsigned short* __restrict__ Qb,
    const unsigned short* __restrict__ Kb,
    const unsigned short* __restrict__ Vtg,
    const unsigned int* __restrict__ mbt,
    unsigned short* __restrict__ Cb)
{
    __shared__ __align__(16) unsigned short Kt[2][AK * 64];   // 2 x 8KB swz
    __shared__ __align__(16) unsigned short Vs[2][64 * AK];   // 2 x 8KB swz

    const int tid  = threadIdx.x;
    const int lane = tid & 63;
    const int w    = tid >> 6;          // wave 0..3: queries w*32..+31
    const int hi   = lane >> 5;         // half-lane
    const int l31  = lane & 31;

    // XCD-chunked bijective swizzle (1024 wgs, 8 XCDs, 128/chunk)
    const int nid = (blockIdx.x & 7) * 128 + (blockIdx.x >> 3);
    const int q0  = (nid & 15) * AQ;
    const int h   = (nid >> 4) & 15;
    const int b   = nid >> 8;

    // global base pointers (loop-invariant)
    const unsigned short* kbase = &Kb [((size_t)(b * L_)) * D_ + h * 64];
    const unsigned short* vbase = &Vtg[((size_t)((b * H_ + h) * 64)) * L_];

    const int q = q0 + w * 32 + l31;    // this lane's query row
    const unsigned int* mrow = &mbt[((size_t)(b * 32) * 2048 + q) * 2];

    // Q fragments (B-operand): qf[dstep] = Q[q][dstep*16 + hi*8 .. +7]
    short8 qf[4];
    #pragma unroll
    for (int ds = 0; ds < 4; ++ds)
        qf[ds] = *(const short8*)
            &Qb[((size_t)(b * L_ + q)) * D_ + h * 64 + ds * 16 + hi * 8];

    f32x16 ot[2];                       // O^T acc: [d-block (32 d each)]
    ot[0] = (f32x16)0.f; ot[1] = (f32x16)0.f;
    float m_run = -INFINITY, l_run = 0.f;

    const int swz = l31 & 7;            // read-side XOR for Kt/Vs chunks

    auto stageK = [&](int bi, int kt) {
        const int k0 = kt * AK;
        #pragma unroll
        for (int i = 0; i < 2; ++i) {
            const int fb = i * 256 + w * 64;
            const int f  = fb + lane;
            const int r  = f >> 3;
            const int cs = (f & 7) ^ (r & 7);
            async_copy16(&kbase[(size_t)(k0 + r) * D_ + cs * 8],
                         (char*)&Kt[bi][0] + fb * 16);
        }
    };
    auto stageV = [&](int bi, int kt) {
        const int k0 = kt * AK;
        #pragma unroll
        for (int i = 0; i < 2; ++i) {
            const int fb = i * 256 + w * 64;
            const int f  = fb + lane;
            const int r  = f >> 3;
            const int cs = (f & 7) ^ (r & 7);
            async_copy16(&vbase[(size_t)r * L_ + k0 + cs * 8],
                         (char*)&Vs[bi][0] + fb * 16);
        }
    };

    // QK of tile kt from Kb[bi] into D0 (keys 0-31), D1 (keys 32-63)
    auto qk = [&](int bi, f32x16& D0, f32x16& D1) {
        #pragma unroll
        for (int ds = 0; ds < 4; ++ds) {
            short8 kf0 = *(const short8*)
                &Kt[bi][(l31) * 64 + ((ds * 2 + hi) ^ swz) * 8];
            short8 kf1 = *(const short8*)
                &Kt[bi][(32 + l31) * 64 + ((ds * 2 + hi) ^ swz) * 8];
            __builtin_amdgcn_s_setprio(1);
            D0 = __builtin_amdgcn_mfma_f32_32x32x16_bf16(
                kf0, qf[ds], ds ? D0 : (f32x16)0.f, 0, 0, 0);
            D1 = __builtin_amdgcn_mfma_f32_32x32x16_bf16(
                kf1, qf[ds], ds ? D1 : (f32x16)0.f, 0, 0, 0);
            __builtin_amdgcn_s_setprio(0);
        }
    };

    f32x16 stA0, stA1, stB0, stB1;

    // one pipelined iteration: P0/P1 = scores(t) [consumed];
    // N0/N1 <- scores(t+1) [computed ahead, adjacent to SM for interleave]
    auto body = [&](int t, f32x16& P0, f32x16& P1, f32x16& N0, f32x16& N1) {
        stageK(t & 1,      (t + 2 < NT) ? t + 2 : NT - 1);
        stageV((t + 1) & 1, (t + 1 < NT) ? t + 1 : NT - 1);
        const uint2 mm = *(const uint2*)&mrow[(size_t)t * 4096];

        // ---- QK(t+1) (MFMA pipe) -- independent of SM(t) below ----------
        qk((t + 1) & 1, N0, N1);

        // ---- SM(t) (VALU) -----------------------------------------------
        // key for P{kr}[reg]: kr*32 + (reg&3) + 8*(reg>>2) + 4*hi
        float rmax = -INFINITY;
        #pragma unroll
        for (int kr = 0; kr < 2; ++kr) {
            f32x16& S = kr ? P1 : P0;
            const unsigned w32 = kr ? mm.y : mm.x;
            #pragma unroll
            for (int s = 0; s < 4; ++s) {
                const unsigned nib = (w32 >> (s * 8 + hi * 4)) & 0xFu;
                #pragma unroll
                for (int r = 0; r < 4; ++r) {
                    float x = S[s * 4 + r];
                    x = ((nib >> r) & 1u) ? x : -INFINITY;
                    S[s * 4 + r] = x;
                    rmax = fmaxf(rmax, x);
                }
            }
        }
        rmax = fmaxf(rmax, __shfl_xor(rmax, 32));
        // T13 defer-max
        if (__any(rmax > m_run + 8.f)) {
            const float mnew  = fmaxf(m_run, rmax);
            const float alpha = __builtin_amdgcn_exp2f(
                m_run - fmaxf(mnew, -1e30f));
            l_run *= alpha;
            #pragma unroll
            for (int db = 0; db < 2; ++db)
                #pragma unroll
                for (int i = 0; i < 16; ++i) ot[db][i] *= alpha;
            m_run = mnew;
        }
        const float msafe = fmaxf(m_run, -1e30f);
        float psum = 0.f;
        #pragma unroll
        for (int kr = 0; kr < 2; ++kr) {
            f32x16& S = kr ? P1 : P0;
            #pragma unroll
            for (int i = 0; i < 16; ++i) {
                const float p = __builtin_amdgcn_exp2f(S[i] - msafe);
                S[i] = p;
                psum += p;
            }
        }
        psum += __shfl_xor(psum, 32);
        l_run += psum;

        // ---- PV(t): O^T += V^T·P^T; pf via cvt_pk + shfl_xor(32) --------
        #pragma unroll
        for (int ks = 0; ks < 4; ++ks) {
            const int sA = (ks & 1) * 2;
            f32x16& S = (ks >> 1) ? P1 : P0;
            short8 vf0 = *(const short8*)
                &Vs[t & 1][(l31) * 64 + ((ks * 2 + hi) ^ swz) * 8];
            short8 vf1 = *(const short8*)
                &Vs[t & 1][(32 + l31) * 64 + ((ks * 2 + hi) ^ swz) * 8];
            unsigned cLo0 = cvt_pk_bf16(S[sA*4+0], S[sA*4+1]);
            unsigned cLo1 = cvt_pk_bf16(S[sA*4+2], S[sA*4+3]);
            unsigned cHi0 = cvt_pk_bf16(S[sA*4+4], S[sA*4+5]);
            unsigned cHi1 = cvt_pk_bf16(S[sA*4+6], S[sA*4+7]);
            const int xLo0 = __shfl_xor((int)cLo0, 32);
            const int xLo1 = __shfl_xor((int)cLo1, 32);
            const int xHi0 = __shfl_xor((int)cHi0, 32);
            const int xHi1 = __shfl_xor((int)cHi1, 32);
            i32x4 tt;
            tt.x = hi ? xHi0 : (int)cLo0;
            tt.y = hi ? xHi1 : (int)cLo1;
            tt.z = hi ? (int)cHi0 : xLo0;
            tt.w = hi ? (int)cHi1 : xLo1;
            const short8 pf = *reinterpret_cast<short8*>(&tt);
            __builtin_amdgcn_s_setprio(1);
            ot[0] = __builtin_amdgcn_mfma_f32_32x32x16_bf16(
                vf0, pf, ot[0], 0, 0, 0);
            ot[1] = __builtin_amdgcn_mfma_f32_32x32x16_bf16(
                vf1, pf, ot[1], 0, 0, 0);
            __builtin_amdgcn_s_setprio(0);
        }

        __syncthreads();   // drains this iter's loads; frees read buffers
    };

    // prologue: K(0),V(0),K(1) staged; scores(0) computed
    stageK(0, 0);
    stageV(0, 0);
    stageK(1, 1);
    __syncthreads();            // tiles 0 (K,V) and 1 (K) ready
    qk(0, stA0, stA1);          // scores(0)
    __syncthreads();            // all waves done reading Kb[0] (iter0 rewrites it)

    for (int t = 0; t < NT; t += 2) {
        body(t,     stA0, stA1, stB0, stB1);
        body(t + 1, stB0, stB1, stA0, stA1);
    }

    // ---- epilogue: normalize, store ctx as bf16 [B,L,D] -----------------
    const float rinv = (l_run > 0.f) ? (1.f / l_run) : 0.f;
    const size_t base = ((size_t)(b * L_ + q)) * D_ + h * 64;
    #pragma unroll
    for (int db = 0; db < 2; ++db)
        #pragma unroll
        for (int s = 0; s < 4; ++s) {
            ushort4 o;
            o.x = f2bf(ot[db][s * 4 + 0] * rinv);
            o.y = f2bf(ot[db][s * 4 + 1] * rinv);
            o.z = f2bf(ot[db][s * 4 + 2] * rinv);
            o.w = f2bf(ot[db][s * 4 + 3] * rinv);
            *(ushort4*)&Cb[base + db * 32 + s * 8 + hi * 4] = o;
        }
}

// ---------------------------------------------------------------------------
extern "C" void kernel_launch(void* const* d_in, const int* in_sizes, int n_in,
                              void* d_out, int out_size, void* d_ws, size_t ws_size,
                              hipStream_t stream)
{
    const float* q    = (const float*)d_in[0];
    const float* k    = (const float*)d_in[1];
    const float* v    = (const float*)d_in[2];
    const int*   mask = (const int*)d_in[3];
    const float* WQ   = (const float*)d_in[4];
    const float* bQ   = (const float*)d_in[5];
    const float* WK   = (const float*)d_in[6];
    const float* bK   = (const float*)d_in[7];
    const float* WV   = (const float*)d_in[8];
    const float* bV   = (const float*)d_in[9];
    const float* WO   = (const float*)d_in[10];
    const float* bO   = (const float*)d_in[11];
    float* out = (float*)d_out;

    const size_t NTOK = (size_t)B_ * L_;        // 8192

    // ws map (128 MiB): bf16 zones
    char* W = (char*)d_ws;
    unsigned short* qin = (unsigned short*)(W);                        // 16MB
    unsigned short* kin = (unsigned short*)(W + ((size_t)16  << 20));  // 16MB
    unsigned short* vin = (unsigned short*)(W + ((size_t)32  << 20));  // 16MB
    unsigned short* qbf = (unsigned short*)(W + ((size_t)48  << 20));  // 16MB
    unsigned short* kbf = (unsigned short*)(W + ((size_t)64  << 20));  // 16MB
    unsigned short* vtb = (unsigned short*)(W + ((size_t)80  << 20));  // 16MB (transposed V)
    unsigned short* cb  = (unsigned short*)(W + ((size_t)96  << 20));  // 16MB
    // WTo reuses vin zone (dead after the fused QKV GEMM); must live in ws,
    // NOT d_out, because the final GEMM writes out over all of d_out.
    unsigned short* WTo = vin;

    // d_out as scratch until final GEMM (all dead before the out-write):
    unsigned int*   mbt32 = (unsigned int*)d_out;                            // 2MB
    unsigned short* WTq = (unsigned short*)((char*)d_out + ((size_t)2 << 20));
    unsigned short* WTk = (unsigned short*)((char*)d_out + ((size_t)4 << 20));
    unsigned short* WTv = (unsigned short*)((char*)d_out + ((size_t)6 << 20));

    pack_mask32_kernel<<<(B_ * L_ * L_) / 256, 256, 0, stream>>>(mask, mbt32);

    const int cvtg = (int)(NTOK * D_ / (256 * 8));   // 4096
    cvt3_bf16_kernel<<<dim3(cvtg, 3), 256, 0, stream>>>(q, k, v, qin, kin, vin);

    trans3_bf16_kernel<<<dim3(32, 32, 3), 256, 0, stream>>>(
        WQ, WK, WV, WTq, WTk, WTv);

    // Projections, bf16 out, one launch. Q gets scale*log2e folded in.
    // V (z==2) is written TRANSPOSED directly into vtb (vtrans fused).
    const float qscale = 0.125f * 1.44269504088896340736f;
    dim3 ggrd3(D_ / 128, NTOK / 128, 3);        // (8, 64, 3) = 1536 wgs
    gemm3_mfma_kernel<<<ggrd3, 256, 0, stream>>>(
        qin, kin, vin, WTq, WTk, WTv, bQ, bK, bV, qbf, kbf, vtb, qscale);

    // WO transpose into vin zone (dead now)
    transpose_bf16_kernel<<<dim3(32, 32), 256, 0, stream>>>(WO, WTo);

    attn_mfma_kernel<<<dim3(1024), 256, 0, stream>>>(qbf, kbf, vtb, mbt32, cb);

    dim3 ggrd(D_ / 128, NTOK / 128);            // (8, 64)
    gemm_mfma_kernel<<<ggrd, 256, 0, stream>>>(cb, WTo, bO, out, (int)NTOK, D_, D_);
}